// Round 1
// baseline (4350.461 us; speedup 1.0000x reference)
//
#include <hip/hip_runtime.h>

#define D_IN 1024
#define D_LAT 32768
#define NROWS 4096

#define BM 128
#define BN 128
#define BK 16

// ---------------- GEMM + JumpReLU: Z = jumprelu(h2 @ W^T + b) ----------------
// A: [NROWS][D_IN] row-major, W: [D_LAT][D_IN] row-major (NT gemm, K contiguous)
__global__ __launch_bounds__(256) void gemm_jumprelu(
    const float* __restrict__ A,
    const float* __restrict__ W,
    const float* __restrict__ bias,
    float* __restrict__ Z)
{
    __shared__ float As[BK][BM];
    __shared__ float Bs[BK][BN];
    const int tid  = threadIdx.x;
    const int row0 = blockIdx.y * BM;
    const int col0 = blockIdx.x * BN;
    const int tx = tid & 15;   // 0..15 (col group)
    const int ty = tid >> 4;   // 0..15 (row group)

    // staging loader mapping: each thread loads 2 rows x float4 along K
    const int lr = tid >> 2;          // 0..63
    const int lk = (tid & 3) << 2;    // 0,4,8,12

    const float* Aptr = A + (size_t)(row0 + lr) * D_IN + lk;
    const float* Wptr = W + (size_t)(col0 + lr) * D_IN + lk;

    float acc[8][8];
#pragma unroll
    for (int i = 0; i < 8; ++i)
#pragma unroll
        for (int j = 0; j < 8; ++j) acc[i][j] = 0.f;

    for (int k0 = 0; k0 < D_IN; k0 += BK) {
        float4 a0 = *(const float4*)(Aptr + k0);
        float4 a1 = *(const float4*)(Aptr + k0 + (size_t)64 * D_IN);
        float4 b0 = *(const float4*)(Wptr + k0);
        float4 b1 = *(const float4*)(Wptr + k0 + (size_t)64 * D_IN);
        As[lk+0][lr] = a0.x; As[lk+1][lr] = a0.y; As[lk+2][lr] = a0.z; As[lk+3][lr] = a0.w;
        As[lk+0][lr+64] = a1.x; As[lk+1][lr+64] = a1.y; As[lk+2][lr+64] = a1.z; As[lk+3][lr+64] = a1.w;
        Bs[lk+0][lr] = b0.x; Bs[lk+1][lr] = b0.y; Bs[lk+2][lr] = b0.z; Bs[lk+3][lr] = b0.w;
        Bs[lk+0][lr+64] = b1.x; Bs[lk+1][lr+64] = b1.y; Bs[lk+2][lr+64] = b1.z; Bs[lk+3][lr+64] = b1.w;
        __syncthreads();
#pragma unroll
        for (int kk = 0; kk < BK; ++kk) {
            float4 fa0 = *(const float4*)&As[kk][ty*8];
            float4 fa1 = *(const float4*)&As[kk][ty*8+4];
            float4 fb0 = *(const float4*)&Bs[kk][tx*8];
            float4 fb1 = *(const float4*)&Bs[kk][tx*8+4];
            float av[8] = {fa0.x,fa0.y,fa0.z,fa0.w,fa1.x,fa1.y,fa1.z,fa1.w};
            float bv[8] = {fb0.x,fb0.y,fb0.z,fb0.w,fb1.x,fb1.y,fb1.z,fb1.w};
#pragma unroll
            for (int i = 0; i < 8; ++i)
#pragma unroll
                for (int j = 0; j < 8; ++j)
                    acc[i][j] = fmaf(av[i], bv[j], acc[i][j]);
        }
        __syncthreads();
    }

    // epilogue: pre = acc + bias; z = relu(pre) + (pre > 1)
#pragma unroll
    for (int i = 0; i < 8; ++i) {
        const int r = row0 + ty*8 + i;
        float out[8];
#pragma unroll
        for (int j = 0; j < 8; ++j) {
            const int c = col0 + tx*8 + j;
            float pre = acc[i][j] + bias[c];
            out[j] = fmaxf(pre, 0.f) + (pre > 1.0f ? 1.0f : 0.0f);
        }
        float4* dst = (float4*)&Z[(size_t)r * D_LAT + col0 + tx*8];
        dst[0] = make_float4(out[0], out[1], out[2], out[3]);
        dst[1] = make_float4(out[4], out[5], out[6], out[7]);
    }
}

// ---------------- In-place per-(row,level) exact top-k zeroing ----------------
// z >= 0 always, so float ordering == uint-bit ordering. 4-pass radix select
// finds the exact k-th largest value; ties at threshold kept by lowest index
// (matches lax.top_k stable tie-break). Histogram via wave-ballot aggregation
// (fp32 exponent bytes concentrate into few bins -> LDS atomics would serialize).
__global__ __launch_bounds__(256) void topk_select(
    float* __restrict__ Z, int start, int n, int k)
{
    __shared__ int hist[256];
    __shared__ unsigned s_thr;
    __shared__ int s_kk;
    __shared__ int s_e;
    __shared__ int s_cut;

    const int tid  = threadIdx.x;
    const int lane = tid & 63;
    float* zrow = Z + (size_t)blockIdx.x * D_LAT + start;

    unsigned target = 0;
    int kk = k;

    for (int shift = 24; shift >= 0; shift -= 8) {
        hist[tid] = 0;
        __syncthreads();
        const unsigned pmask = (shift == 24) ? 0u : (0xFFFFFFFFu << (shift + 8));
        for (int i0 = 0; i0 < n; i0 += 256) {
            const int i = i0 + tid;     // n is a multiple of 256 for all levels
            const unsigned u = __float_as_uint(zrow[i]);
            const bool m = ((u & pmask) == target);
            const int byte = (int)((u >> shift) & 255u);
            // wave-aggregated histogram: one atomic per distinct byte per wave
            unsigned long long rem = __ballot(m);
            while (rem) {
                const int leader = __ffsll((unsigned long long)rem) - 1;
                const int lv = __shfl(byte, leader);
                const unsigned long long same = __ballot(m && (byte == lv));
                if (lane == leader) atomicAdd(&hist[lv], (int)__popcll(same));
                rem &= ~same;
            }
        }
        __syncthreads();
        if (tid == 0) {
            int cum = 0;
            int b = 255;
            for (; b > 0; --b) {
                if (cum + hist[b] >= kk) break;
                cum += hist[b];
            }
            s_thr = target | ((unsigned)b << shift);
            s_kk  = kk - cum;
        }
        __syncthreads();
        target = s_thr;
        kk     = s_kk;
        __syncthreads();
    }

    const unsigned thr = target;
    const int q = kk;              // how many threshold-equal elements to keep

    // count elements exactly equal to thr
    if (tid == 0) s_e = 0;
    __syncthreads();
    for (int i0 = 0; i0 < n; i0 += 256) {
        const int i = i0 + tid;
        const bool eq = (__float_as_uint(zrow[i]) == thr);
        const unsigned long long b = __ballot(eq);
        if (lane == 0 && b) atomicAdd(&s_e, (int)__popcll(b));
    }
    __syncthreads();
    if (s_e == q) {
        if (tid == 0) s_cut = n;   // keep every threshold-equal element
    } else if (tid == 0) {
        // rare: multiple ties at threshold -> keep first q by index
        int cnt = 0, cut = -1;
        for (int i = 0; i < n; ++i) {
            if (__float_as_uint(zrow[i]) == thr) {
                if (++cnt == q) { cut = i; break; }
            }
        }
        s_cut = cut;
    }
    __syncthreads();
    const int cut = s_cut;

    for (int i0 = 0; i0 < n; i0 += 256) {
        const int i = i0 + tid;
        const float z = zrow[i];
        const unsigned u = __float_as_uint(z);
        const bool keep = (u > thr) || (u == thr && i <= cut);
        zrow[i] = keep ? z : 0.f;
    }
}

extern "C" void kernel_launch(void* const* d_in, const int* in_sizes, int n_in,
                              void* d_out, int out_size, void* d_ws, size_t ws_size,
                              hipStream_t stream)
{
    const float* h2   = (const float*)d_in[0];
    const float* Wenc = (const float*)d_in[1];
    const float* benc = (const float*)d_in[2];
    float* Z = (float*)d_out;

    dim3 grid(D_LAT / BN, NROWS / BM);
    gemm_jumprelu<<<grid, dim3(256), 0, stream>>>(h2, Wenc, benc, Z);

    // nested per-level top-k, in place on Z
    topk_select<<<dim3(NROWS), dim3(256), 0, stream>>>(Z, 0,    2048,  32);
    topk_select<<<dim3(NROWS), dim3(256), 0, stream>>>(Z, 2048, 6144,  64);
    topk_select<<<dim3(NROWS), dim3(256), 0, stream>>>(Z, 8192, 24576, 128);
}

// Round 2
// 3606.914 us; speedup vs baseline: 1.2061x; 1.2061x over previous
//
#include <hip/hip_runtime.h>

#define NROWS 4096
#define DK    1024
#define DLAT  32768

typedef float  f32x4  __attribute__((ext_vector_type(4)));
typedef short  bf16x8 __attribute__((ext_vector_type(8)));
typedef unsigned short u16;

// d_out (512 MB) region map (bytes):
//   [0, 256M)   approx pre, bf16 [NROWS][DLAT]
//   [256M,320M) W bf16 [DLAT][DK]
//   [320M,328M) A bf16 [NROWS][DK]
#define WB_OFF ((size_t)NROWS * DLAT * 2)
#define AB_OFF (WB_OFF + (size_t)DLAT * DK * 2)

#define MARGIN 0.06f
#define CAP    256
#define NPAIR  224   // 32+64+128 kept per row

__device__ __forceinline__ u16 f2bf(float f) {
    unsigned u = __float_as_uint(f);
    return (u16)((u + 0x7FFF + ((u >> 16) & 1)) >> 16);
}

// ---------------- P0: fp32 -> bf16 copies of W and A ----------------
__global__ __launch_bounds__(256) void convert_bf16(
    const float* __restrict__ W, const float* __restrict__ A,
    u16* __restrict__ Wb, u16* __restrict__ Ab)
{
    const size_t NW = (size_t)DLAT * DK / 4;
    const size_t NA = (size_t)NROWS * DK / 4;
    size_t i = (size_t)blockIdx.x * 256 + threadIdx.x;
    const size_t stride = (size_t)gridDim.x * 256;
    for (; i < NW + NA; i += stride) {
        const float4 v = (i < NW) ? ((const float4*)W)[i] : ((const float4*)A)[i - NW];
        ushort4 o;
        o.x = f2bf(v.x); o.y = f2bf(v.y); o.z = f2bf(v.z); o.w = f2bf(v.w);
        if (i < NW) ((ushort4*)Wb)[i] = o; else ((ushort4*)Ab)[i - NW] = o;
    }
}

// ---------------- P1: bf16 MFMA GEMM -> approx pre (bf16) ----------------
// A[M][K] x W[N][K]^T, 128x128 tile, BK=32, 4 waves each owning a 64x64 quadrant.
__global__ __launch_bounds__(256) void gemm_approx(
    const u16* __restrict__ Ab, const u16* __restrict__ Wb,
    const float* __restrict__ bias, u16* __restrict__ approx)
{
    __shared__ __align__(16) u16 sA[128 * 32];
    __shared__ __align__(16) u16 sB[128 * 32];
    const int tid  = threadIdx.x;
    const int lane = tid & 63;
    const int wv   = tid >> 6;
    const int wr   = wv >> 1, wc = wv & 1;
    const int cb = blockIdx.x, rb = blockIdx.y;

    f32x4 acc[4][4] = {};

    // global_load_lds chunk map: chunk c in [0,512): row=c>>2, kpart=c&3 (8 bf16 = 16B each)
    u16* baseA0 = &sA[(size_t)(0 * 256 + wv * 64) * 8];
    u16* baseA1 = &sA[(size_t)(1 * 256 + wv * 64) * 8];
    u16* baseB0 = &sB[(size_t)(0 * 256 + wv * 64) * 8];
    u16* baseB1 = &sB[(size_t)(1 * 256 + wv * 64) * 8];

    const int c0 = tid, c1 = tid + 256;
    const u16* gA0 = Ab + ((size_t)(rb * 128 + (c0 >> 2)) * DK + (c0 & 3) * 8);
    const u16* gA1 = Ab + ((size_t)(rb * 128 + (c1 >> 2)) * DK + (c1 & 3) * 8);
    const u16* gB0 = Wb + ((size_t)(cb * 128 + (c0 >> 2)) * DK + (c0 & 3) * 8);
    const u16* gB1 = Wb + ((size_t)(cb * 128 + (c1 >> 2)) * DK + (c1 & 3) * 8);

    const int lrow = lane & 15;
    const int lk   = (lane >> 4) * 8;

    for (int kt = 0; kt < DK / 32; ++kt) {
        const int kb = kt * 32;
        __builtin_amdgcn_global_load_lds((const __attribute__((address_space(1))) void*)(gA0 + kb),
                                         (__attribute__((address_space(3))) void*)baseA0, 16, 0, 0);
        __builtin_amdgcn_global_load_lds((const __attribute__((address_space(1))) void*)(gA1 + kb),
                                         (__attribute__((address_space(3))) void*)baseA1, 16, 0, 0);
        __builtin_amdgcn_global_load_lds((const __attribute__((address_space(1))) void*)(gB0 + kb),
                                         (__attribute__((address_space(3))) void*)baseB0, 16, 0, 0);
        __builtin_amdgcn_global_load_lds((const __attribute__((address_space(1))) void*)(gB1 + kb),
                                         (__attribute__((address_space(3))) void*)baseB1, 16, 0, 0);
        __syncthreads();   // compiler drains vmcnt(0) before s_barrier

        bf16x8 af[4], bfr[4];
#pragma unroll
        for (int m = 0; m < 4; ++m)
            af[m] = *(const bf16x8*)&sA[(size_t)(wr * 64 + m * 16 + lrow) * 32 + lk];
#pragma unroll
        for (int n = 0; n < 4; ++n)
            bfr[n] = *(const bf16x8*)&sB[(size_t)(wc * 64 + n * 16 + lrow) * 32 + lk];
#pragma unroll
        for (int m = 0; m < 4; ++m)
#pragma unroll
            for (int n = 0; n < 4; ++n)
                acc[m][n] = __builtin_amdgcn_mfma_f32_16x16x32_bf16(af[m], bfr[n], acc[m][n], 0, 0, 0);
        __syncthreads();
    }

    // epilogue: C/D layout col=lane&15, row=(lane>>4)*4+reg (m89-verified)
    const int r0  = rb * 128 + wr * 64;
    const int cc0 = cb * 128 + wc * 64;
    const int lr4 = (lane >> 4) * 4;
#pragma unroll
    for (int n = 0; n < 4; ++n) {
        const int col = cc0 + n * 16 + lrow;
        const float bv = bias[col];
#pragma unroll
        for (int m = 0; m < 4; ++m)
#pragma unroll
            for (int r = 0; r < 4; ++r)
                approx[(size_t)(r0 + m * 16 + lr4 + r) * DLAT + col] = f2bf(acc[m][n][r] + bv);
    }
}

// ---------------- P2: per-row candidate select (radix on bf16 keys) + exact rescore ----------------
__global__ __launch_bounds__(256) void select_rescore(
    const u16* __restrict__ approx, const float* __restrict__ h2,
    const float* __restrict__ W, const float* __restrict__ bias,
    float* __restrict__ pv, int* __restrict__ pc)
{
    __shared__ __align__(16) u16 keys[DLAT];   // 64 KB, order-preserving transformed bf16
    __shared__ __align__(16) float sAr[DK];    // 4 KB, exact fp32 A row
    __shared__ int hist[256];
    __shared__ u16 ccol[CAP];
    __shared__ float cz[CAP];
    __shared__ int s_cnt, s_b1, s_kk;

    const int tid = threadIdx.x, lane = tid & 63, wv = tid >> 6;
    const int row = blockIdx.x;

    for (int i = tid; i < DK / 4; i += 256)
        ((float4*)sAr)[i] = ((const float4*)(h2 + (size_t)row * DK))[i];

    const u16* arow = approx + (size_t)row * DLAT;
    for (int i = tid; i < DLAT / 4; i += 256) {
        ushort4 v = ((const ushort4*)arow)[i];
        ushort4 o;
        o.x = (v.x & 0x8000) ? (u16)~v.x : (u16)(v.x | 0x8000);
        o.y = (v.y & 0x8000) ? (u16)~v.y : (u16)(v.y | 0x8000);
        o.z = (v.z & 0x8000) ? (u16)~v.z : (u16)(v.z | 0x8000);
        o.w = (v.w & 0x8000) ? (u16)~v.w : (u16)(v.w | 0x8000);
        ((ushort4*)keys)[i] = o;
    }
    __syncthreads();

    const int LSTART[3] = {0, 2048, 8192};
    const int LN[3]     = {2048, 6144, 24576};
    const int LK_[3]    = {32, 64, 128};
    const int PBASE[3]  = {0, 32, 96};

    for (int lv = 0; lv < 3; ++lv) {
        const int start = LSTART[lv], n = LN[lv], k = LK_[lv], pbase = PBASE[lv];

        // pass 1: histogram of high byte (wave-aggregated; few distinct exponent bins)
        hist[tid] = 0;
        __syncthreads();
        for (int i = start + tid; i < start + n; i += 256) {
            int b = keys[i] >> 8;
            unsigned long long rem = __ballot(true);
            while (rem) {
                const int leader = __ffsll(rem) - 1;
                const int lb = __shfl(b, leader);
                const unsigned long long same = __ballot(b == lb);
                if (lane == leader) atomicAdd(&hist[lb], (int)__popcll(same));
                rem &= ~same;
            }
        }
        __syncthreads();
        if (tid == 0) {
            int cum = 0, b = 255;
            for (; b > 0; --b) { if (cum + hist[b] >= k) break; cum += hist[b]; }
            s_b1 = b; s_kk = k - cum;
        }
        __syncthreads();
        const int b1 = s_b1;
        int kk = s_kk;
        hist[tid] = 0;
        __syncthreads();
        // pass 2: low byte among keys with high byte == b1
        for (int i = start + tid; i < start + n; i += 256) {
            const u16 ky = keys[i];
            const bool m = (ky >> 8) == b1;
            const int b = ky & 255;
            unsigned long long rem = __ballot(m);
            while (rem) {
                const int leader = __ffsll(rem) - 1;
                const int lb = __shfl(b, leader);
                const unsigned long long same = __ballot(m && b == lb);
                if (lane == leader) atomicAdd(&hist[lb], (int)__popcll(same));
                rem &= ~same;
            }
        }
        __syncthreads();
        if (tid == 0) {
            int cum = 0, b = 255;
            for (; b > 0; --b) { if (cum + hist[b] >= kk) break; cum += hist[b]; }
            s_b1 = (b1 << 8) | b;
            s_cnt = 0;
        }
        __syncthreads();
        const u16 kq = (u16)s_b1;
        const u16 ub = (kq & 0x8000) ? (u16)(kq ^ 0x8000) : (u16)(~kq);
        const float vk = __uint_as_float((unsigned)ub << 16);
        const float thr = vk - MARGIN;

        // candidate collect
        for (int i = start + tid; i < start + n; i += 256) {
            const u16 ky = keys[i];
            const u16 uu = (ky & 0x8000) ? (u16)(ky ^ 0x8000) : (u16)(~ky);
            const float f = __uint_as_float((unsigned)uu << 16);
            if (f >= thr) {
                const int p = atomicAdd(&s_cnt, 1);
                if (p < CAP) ccol[p] = (u16)i;
            }
        }
        __syncthreads();
        const int cnt = min(s_cnt, CAP);

        // exact fp32 rescore, one wave per candidate
        for (int c = wv; c < cnt; c += 4) {
            const int col = ccol[c];
            const float* wrow = W + (size_t)col * DK;
            float p = 0.f;
#pragma unroll
            for (int j = 0; j < 4; ++j) {
                const float4 w4 = ((const float4*)wrow)[j * 64 + lane];
                const float4 a4 = ((const float4*)sAr)[j * 64 + lane];
                p = fmaf(w4.x, a4.x, p); p = fmaf(w4.y, a4.y, p);
                p = fmaf(w4.z, a4.z, p); p = fmaf(w4.w, a4.w, p);
            }
#pragma unroll
            for (int s = 32; s; s >>= 1) p += __shfl_xor(p, s);
            const float pre = p + bias[col];
            const float z = fmaxf(pre, 0.f) + (pre > 1.f ? 1.f : 0.f);
            if (lane == 0) cz[c] = z;
        }
        __syncthreads();

        // exact stable top-k among candidates: rank by (z desc, col asc)
        for (int c = tid; c < cnt; c += 256) {
            const unsigned long long my =
                ((unsigned long long)__float_as_uint(cz[c]) << 32) | (0xFFFFFFFFu - (unsigned)ccol[c]);
            int rank = 0;
            for (int d = 0; d < cnt; ++d) {
                const unsigned long long kd =
                    ((unsigned long long)__float_as_uint(cz[d]) << 32) | (0xFFFFFFFFu - (unsigned)ccol[d]);
                rank += (kd > my);
            }
            if (rank < k) {
                pv[(size_t)row * NPAIR + pbase + rank] = cz[c];
                pc[(size_t)row * NPAIR + pbase + rank] = ccol[c];
            }
        }
        __syncthreads();
    }
}

// ---------------- P3: zero the output ----------------
__global__ __launch_bounds__(256) void zero_out(float4* __restrict__ Z) {
    const size_t N4 = (size_t)NROWS * DLAT / 4;
    const size_t stride = (size_t)gridDim.x * 256;
    const float4 z = {0.f, 0.f, 0.f, 0.f};
    for (size_t i = (size_t)blockIdx.x * 256 + threadIdx.x; i < N4; i += stride) Z[i] = z;
}

// ---------------- P4: scatter exact values ----------------
__global__ __launch_bounds__(256) void scatter_out(
    const float* __restrict__ pv, const int* __restrict__ pc, float* __restrict__ Z)
{
    const int row = blockIdx.x, t = threadIdx.x;
    if (t < NPAIR) {
        const float v = pv[(size_t)row * NPAIR + t];
        const int col = pc[(size_t)row * NPAIR + t];
        Z[(size_t)row * DLAT + col] = v;
    }
}

extern "C" void kernel_launch(void* const* d_in, const int* in_sizes, int n_in,
                              void* d_out, int out_size, void* d_ws, size_t ws_size,
                              hipStream_t stream)
{
    const float* h2   = (const float*)d_in[0];
    const float* Wenc = (const float*)d_in[1];
    const float* benc = (const float*)d_in[2];
    float* Z = (float*)d_out;

    u16* approx = (u16*)d_out;
    u16* Wb = (u16*)((char*)d_out + WB_OFF);
    u16* Ab = (u16*)((char*)d_out + AB_OFF);
    float* pv = (float*)d_ws;
    int*   pc = (int*)((char*)d_ws + (size_t)NROWS * NPAIR * 4);

    convert_bf16<<<2048, 256, 0, stream>>>(Wenc, h2, Wb, Ab);
    gemm_approx<<<dim3(DLAT / 128, NROWS / 128), 256, 0, stream>>>(Ab, Wb, benc, approx);
    select_rescore<<<NROWS, 256, 0, stream>>>(approx, h2, Wenc, benc, pv, pc);
    zero_out<<<2048, 256, 0, stream>>>((float4*)Z);
    scatter_out<<<NROWS, 256, 0, stream>>>(pv, pc, Z);
}

// Round 3
// 761.670 us; speedup vs baseline: 5.7117x; 4.7355x over previous
//
#include <hip/hip_runtime.h>

#define NROWS 4096
#define DK    1024
#define DLAT  32768
#define NUNIT (NROWS * 3)

typedef float  f32x4  __attribute__((ext_vector_type(4)));
typedef short  bf16x8 __attribute__((ext_vector_type(8)));
typedef unsigned short u16;

// d_out (512 MB) region map (bytes):
//   [0, 256M)    approx pre, u16 fixed-point [NROWS][DLAT]  (q = rn(pre*4096)+32768)
//   [256M,320M)  W bf16 [DLAT][DK]
//   [320M,328M)  A bf16 [NROWS][DK]
//   [328M,~350M) candidate lists
#define APX_BYTES ((size_t)NROWS * DLAT * 2)
#define WB_OFF  APX_BYTES
#define AB_OFF  (WB_OFF + (size_t)DLAT * DK * 2)
#define LST_OFF (AB_OFF + (size_t)NROWS * DK * 2)

#define SCAP 128
#define BCAP 160
#define SCOL_OFF  LST_OFF
#define SVAL_OFF  (SCOL_OFF + (size_t)NUNIT * SCAP * 2)
#define BCOL_OFF  (SVAL_OFF + (size_t)NUNIT * SCAP * 4)
#define BPRE_OFF  (BCOL_OFF + (size_t)NUNIT * BCAP * 2)
#define CNT_OFF   (BPRE_OFF + (size_t)NUNIT * BCAP * 4)

#define QINV 2.44140625e-4f
#define EQ2  82      // 2*E in q units (E = 0.01)
#define NPAIR 224    // 32+64+128

__device__ __forceinline__ u16 f2bf(float f) {
    unsigned u = __float_as_uint(f);
    return (u16)((u + 0x7FFF + ((u >> 16) & 1)) >> 16);
}

// ---------------- P0: fp32 -> bf16 copies of W and A ----------------
__global__ __launch_bounds__(256) void convert_bf16(
    const float* __restrict__ W, const float* __restrict__ A,
    u16* __restrict__ Wb, u16* __restrict__ Ab)
{
    const size_t NW = (size_t)DLAT * DK / 4;
    const size_t NA = (size_t)NROWS * DK / 4;
    size_t i = (size_t)blockIdx.x * 256 + threadIdx.x;
    const size_t stride = (size_t)gridDim.x * 256;
    for (; i < NW + NA; i += stride) {
        const float4 v = (i < NW) ? ((const float4*)W)[i] : ((const float4*)A)[i - NW];
        ushort4 o;
        o.x = f2bf(v.x); o.y = f2bf(v.y); o.z = f2bf(v.z); o.w = f2bf(v.w);
        if (i < NW) ((ushort4*)Wb)[i] = o; else ((ushort4*)Ab)[i - NW] = o;
    }
}

// ---------------- P1: bf16 MFMA GEMM -> approx pre (u16 fixed point) ----------------
__global__ __launch_bounds__(256) void gemm_approx(
    const u16* __restrict__ Ab, const u16* __restrict__ Wb,
    const float* __restrict__ bias, u16* __restrict__ approx)
{
    __shared__ __align__(16) u16 sA[128 * 32];
    __shared__ __align__(16) u16 sB[128 * 32];
    const int tid  = threadIdx.x;
    const int lane = tid & 63;
    const int wv   = tid >> 6;
    const int wr   = wv >> 1, wc = wv & 1;
    const int cb = blockIdx.x, rb = blockIdx.y;

    f32x4 acc[4][4] = {};

    u16* baseA0 = &sA[(size_t)(0 * 256 + wv * 64) * 8];
    u16* baseA1 = &sA[(size_t)(1 * 256 + wv * 64) * 8];
    u16* baseB0 = &sB[(size_t)(0 * 256 + wv * 64) * 8];
    u16* baseB1 = &sB[(size_t)(1 * 256 + wv * 64) * 8];

    const int c0 = tid, c1 = tid + 256;
    const u16* gA0 = Ab + ((size_t)(rb * 128 + (c0 >> 2)) * DK + (c0 & 3) * 8);
    const u16* gA1 = Ab + ((size_t)(rb * 128 + (c1 >> 2)) * DK + (c1 & 3) * 8);
    const u16* gB0 = Wb + ((size_t)(cb * 128 + (c0 >> 2)) * DK + (c0 & 3) * 8);
    const u16* gB1 = Wb + ((size_t)(cb * 128 + (c1 >> 2)) * DK + (c1 & 3) * 8);

    const int lrow = lane & 15;
    const int lk   = (lane >> 4) * 8;

    for (int kt = 0; kt < DK / 32; ++kt) {
        const int kb = kt * 32;
        __builtin_amdgcn_global_load_lds((const __attribute__((address_space(1))) void*)(gA0 + kb),
                                         (__attribute__((address_space(3))) void*)baseA0, 16, 0, 0);
        __builtin_amdgcn_global_load_lds((const __attribute__((address_space(1))) void*)(gA1 + kb),
                                         (__attribute__((address_space(3))) void*)baseA1, 16, 0, 0);
        __builtin_amdgcn_global_load_lds((const __attribute__((address_space(1))) void*)(gB0 + kb),
                                         (__attribute__((address_space(3))) void*)baseB0, 16, 0, 0);
        __builtin_amdgcn_global_load_lds((const __attribute__((address_space(1))) void*)(gB1 + kb),
                                         (__attribute__((address_space(3))) void*)baseB1, 16, 0, 0);
        __syncthreads();

        bf16x8 af[4], bfr[4];
#pragma unroll
        for (int m = 0; m < 4; ++m)
            af[m] = *(const bf16x8*)&sA[(size_t)(wr * 64 + m * 16 + lrow) * 32 + lk];
#pragma unroll
        for (int n = 0; n < 4; ++n)
            bfr[n] = *(const bf16x8*)&sB[(size_t)(wc * 64 + n * 16 + lrow) * 32 + lk];
#pragma unroll
        for (int m = 0; m < 4; ++m)
#pragma unroll
            for (int n = 0; n < 4; ++n)
                acc[m][n] = __builtin_amdgcn_mfma_f32_16x16x32_bf16(af[m], bfr[n], acc[m][n], 0, 0, 0);
        __syncthreads();
    }

    const int r0  = rb * 128 + wr * 64;
    const int cc0 = cb * 128 + wc * 64;
    const int lr4 = (lane >> 4) * 4;
#pragma unroll
    for (int n = 0; n < 4; ++n) {
        const int col = cc0 + n * 16 + lrow;
        const float bv = bias[col];
#pragma unroll
        for (int m = 0; m < 4; ++m)
#pragma unroll
            for (int r = 0; r < 4; ++r) {
                const float pre = acc[m][n][r] + bv;
                int q = __float2int_rn(pre * 4096.f) + 32768;
                q = min(max(q, 0), 65535);
                approx[(size_t)(r0 + m * 16 + lr4 + r) * DLAT + col] = (u16)q;
            }
    }
}

// ---------------- P2: per-(row,level) histogram select -> sure/band lists ----------------
__global__ __launch_bounds__(256) void select_band(
    const u16* __restrict__ apx,
    u16* __restrict__ scol, float* __restrict__ sval,
    u16* __restrict__ bcol, int* __restrict__ cnts)
{
    __shared__ int hist[4096];
    __shared__ int wsum[4];
    __shared__ int s_B, s_ns, s_nb;

    const int tid = threadIdx.x, lane = tid & 63, wv = tid >> 6;
    const int u = blockIdx.x;
    const int row = u / 3, lvl = u - 3 * row;
    const int LSTART[3] = {0, 2048, 8192};
    const int LN[3]     = {2048, 6144, 24576};
    const int LK_[3]    = {32, 64, 128};
    const int start = LSTART[lvl], n = LN[lvl], k = LK_[lvl];

#pragma unroll
    for (int i = 0; i < 16; ++i) hist[tid * 16 + i] = 0;
    if (tid == 0) { s_ns = 0; s_nb = 0; }
    __syncthreads();

    const uint4* base = (const uint4*)(apx + (size_t)row * DLAT + start);
    const int n8 = n >> 3;
    for (int i = tid; i < n8; i += 256) {
        const uint4 v = base[i];
        atomicAdd(&hist[(v.x & 0xFFFF) >> 4], 1);
        atomicAdd(&hist[(v.x >> 16) >> 4], 1);
        atomicAdd(&hist[(v.y & 0xFFFF) >> 4], 1);
        atomicAdd(&hist[(v.y >> 16) >> 4], 1);
        atomicAdd(&hist[(v.z & 0xFFFF) >> 4], 1);
        atomicAdd(&hist[(v.z >> 16) >> 4], 1);
        atomicAdd(&hist[(v.w & 0xFFFF) >> 4], 1);
        atomicAdd(&hist[(v.w >> 16) >> 4], 1);
    }
    __syncthreads();

    // suffix scan from top: chunk t covers bins [b0-15, b0], b0 = 4095-16t
    const int b0 = 4095 - 16 * tid;
    int part = 0;
#pragma unroll
    for (int i = 0; i < 16; ++i) part += hist[b0 - i];
    int incl = part;
#pragma unroll
    for (int s = 1; s < 64; s <<= 1) {
        const int t = __shfl_up(incl, s);
        if (lane >= s) incl += t;
    }
    if (lane == 63) wsum[wv] = incl;
    __syncthreads();
    int woff = 0;
    for (int j = 0; j < wv; ++j) woff += wsum[j];
    const int above = woff + incl - part;
    if (above < k && above + part >= k) {
        int run = above, B = -1;
        for (int i = 0; i < 16; ++i) {
            run += hist[b0 - i];
            if (run >= k) { B = b0 - i; break; }
        }
        s_B = B;
    }
    __syncthreads();

    const int qsure = s_B * 16 + 16 + EQ2;   // q >= this => definitely in top-k
    const int qband = s_B * 16 - EQ2;        // q >= this (else definitely out)

    for (int i = tid; i < n8; i += 256) {
        const uint4 v = base[i];
        const int col0 = start + i * 8;
        unsigned qs[8] = { v.x & 0xFFFF, v.x >> 16, v.y & 0xFFFF, v.y >> 16,
                           v.z & 0xFFFF, v.z >> 16, v.w & 0xFFFF, v.w >> 16 };
#pragma unroll
        for (int j = 0; j < 8; ++j) {
            const int q = (int)qs[j];
            if (q >= qsure) {
                const int p = atomicAdd(&s_ns, 1);
                if (p < SCAP) {
                    scol[(size_t)u * SCAP + p] = (u16)(col0 + j);
                    const float a = (q - 32768) * QINV;
                    sval[(size_t)u * SCAP + p] = fmaxf(a, 0.f) + (a > 1.f ? 1.f : 0.f);
                }
            } else if (q >= qband) {
                const int p = atomicAdd(&s_nb, 1);
                if (p < BCAP) bcol[(size_t)u * BCAP + p] = (u16)(col0 + j);
            }
        }
    }
    __syncthreads();
    if (tid == 0) { cnts[2 * u] = s_ns; cnts[2 * u + 1] = s_nb; }
}

// ---------------- P3: exact fp32 rescore of band candidates ----------------
__global__ __launch_bounds__(256) void rescore(
    const u16* __restrict__ bcol, const int* __restrict__ cnts,
    const float* __restrict__ h2, const float* __restrict__ W,
    const float* __restrict__ bias, float* __restrict__ bpre)
{
    __shared__ __align__(16) float sAr[DK];
    const int tid = threadIdx.x, lane = tid & 63, wv = tid >> 6;
    const int u = blockIdx.x;
    const int row = u / 3;

    for (int i = tid; i < DK / 4; i += 256)
        ((float4*)sAr)[i] = ((const float4*)(h2 + (size_t)row * DK))[i];
    __syncthreads();

    const int bc = min(cnts[2 * u + 1], BCAP);
    for (int c = wv; c < bc; c += 4) {
        const int col = bcol[(size_t)u * BCAP + c];
        const float* wrow = W + (size_t)col * DK;
        float p = 0.f;
#pragma unroll
        for (int j = 0; j < 4; ++j) {
            const float4 w4 = ((const float4*)wrow)[j * 64 + lane];
            const float4 a4 = ((const float4*)sAr)[j * 64 + lane];
            p = fmaf(w4.x, a4.x, p); p = fmaf(w4.y, a4.y, p);
            p = fmaf(w4.z, a4.z, p); p = fmaf(w4.w, a4.w, p);
        }
#pragma unroll
        for (int s = 32; s; s >>= 1) p += __shfl_xor(p, s);
        if (lane == 0) bpre[(size_t)u * BCAP + c] = p + bias[col];
    }
}

// ---------------- P4: final per-(row,level) selection -> (val,col) pairs ----------------
__global__ __launch_bounds__(256) void finalize(
    const u16* __restrict__ scol, const float* __restrict__ sval,
    const u16* __restrict__ bcol, const float* __restrict__ bpre,
    const int* __restrict__ cnts,
    float* __restrict__ pv, int* __restrict__ pc)
{
    __shared__ float bp[BCAP];
    __shared__ u16 bcm[BCAP];
    const int tid = threadIdx.x;
    const int u = blockIdx.x;
    const int row = u / 3, lvl = u - 3 * row;
    const int LK_[3] = {32, 64, 128};
    const int PB_[3] = {0, 32, 96};
    const int k = LK_[lvl], pbase = PB_[lvl];

    const int m  = min(cnts[2 * u], SCAP);
    const int bc = min(cnts[2 * u + 1], BCAP);
    const int need = max(k - m, 0);

    const size_t obase = (size_t)row * NPAIR + pbase;
    // sure entries (approx values, provably in top-k)
    if (tid < m && tid < k) {
        pv[obase + tid] = sval[(size_t)u * SCAP + tid];
        pc[obase + tid] = scol[(size_t)u * SCAP + tid];
    }
    for (int c = tid; c < bc; c += 256) {
        bp[c]  = bpre[(size_t)u * BCAP + c];
        bcm[c] = bcol[(size_t)u * BCAP + c];
    }
    __syncthreads();

    // stable top-(need) among band by exact (pre desc, col asc)
    for (int c = tid; c < bc; c += 256) {
        const float pc_ = bp[c];
        const int col_c = bcm[c];
        int rank = 0;
        for (int d = 0; d < bc; ++d) {
            const float pd = bp[d];
            rank += (pd > pc_) || (pd == pc_ && bcm[d] < col_c);
        }
        if (rank < need) {
            const float z = fmaxf(pc_, 0.f) + (pc_ > 1.f ? 1.f : 0.f);
            pv[obase + m + rank] = z;
            pc[obase + m + rank] = col_c;
        }
    }
}

// ---------------- P5: zero the output ----------------
__global__ __launch_bounds__(256) void zero_out(float4* __restrict__ Z) {
    const size_t N4 = (size_t)NROWS * DLAT / 4;
    const size_t stride = (size_t)gridDim.x * 256;
    const float4 z = {0.f, 0.f, 0.f, 0.f};
    for (size_t i = (size_t)blockIdx.x * 256 + threadIdx.x; i < N4; i += stride) Z[i] = z;
}

// ---------------- P6: scatter final values ----------------
__global__ __launch_bounds__(256) void scatter_out(
    const float* __restrict__ pv, const int* __restrict__ pc, float* __restrict__ Z)
{
    const int row = blockIdx.x, t = threadIdx.x;
    if (t < NPAIR) {
        const float v = pv[(size_t)row * NPAIR + t];
        const int col = pc[(size_t)row * NPAIR + t];
        Z[(size_t)row * DLAT + col] = v;
    }
}

extern "C" void kernel_launch(void* const* d_in, const int* in_sizes, int n_in,
                              void* d_out, int out_size, void* d_ws, size_t ws_size,
                              hipStream_t stream)
{
    const float* h2   = (const float*)d_in[0];
    const float* Wenc = (const float*)d_in[1];
    const float* benc = (const float*)d_in[2];
    char* ob = (char*)d_out;

    u16*   approx = (u16*)ob;
    u16*   Wb   = (u16*)(ob + WB_OFF);
    u16*   Ab   = (u16*)(ob + AB_OFF);
    u16*   scol = (u16*)(ob + SCOL_OFF);
    float* sval = (float*)(ob + SVAL_OFF);
    u16*   bcol = (u16*)(ob + BCOL_OFF);
    float* bpre = (float*)(ob + BPRE_OFF);
    int*   cnts = (int*)(ob + CNT_OFF);

    float* pv = (float*)d_ws;
    int*   pc = (int*)((char*)d_ws + (size_t)NROWS * NPAIR * 4);

    convert_bf16<<<2048, 256, 0, stream>>>(Wenc, h2, Wb, Ab);
    gemm_approx<<<dim3(DLAT / 128, NROWS / 128), 256, 0, stream>>>(Ab, Wb, benc, approx);
    select_band<<<NUNIT, 256, 0, stream>>>(approx, scol, sval, bcol, cnts);
    rescore<<<NUNIT, 256, 0, stream>>>(bcol, cnts, h2, Wenc, benc, bpre);
    finalize<<<NUNIT, 256, 0, stream>>>(scol, sval, bcol, bpre, cnts, pv, pc);
    zero_out<<<2048, 256, 0, stream>>>((float4*)(void*)d_out);
    scatter_out<<<NROWS, 256, 0, stream>>>(pv, pc, (float*)d_out);
}

// Round 4
// 642.001 us; speedup vs baseline: 6.7764x; 1.1864x over previous
//
#include <hip/hip_runtime.h>

#define NROWS 4096
#define DK    1024
#define DLAT  32768
#define NUNIT (NROWS * 3)

typedef float  f32x4  __attribute__((ext_vector_type(4)));
typedef short  bf16x8 __attribute__((ext_vector_type(8)));
typedef unsigned short u16;

// d_out (512 MB) region map (bytes):
//   [0, 256M)    approx pre, u16 fixed-point [NROWS][DLAT]  (q = rn(pre*4096)+32768)
//   [256M,320M)  W bf16 [DLAT][DK]
//   [320M,328M)  A bf16 [NROWS][DK]
#define APX_BYTES ((size_t)NROWS * DLAT * 2)
#define WB_OFF  APX_BYTES
#define AB_OFF  (WB_OFF + (size_t)DLAT * DK * 2)

#define BCAP 160
#define QINV 2.44140625e-4f
#define EQ2  82      // 2*E in q units (E = 0.01)
#define NPAIR 224    // 32+64+128

__device__ __forceinline__ u16 f2bf(float f) {
    unsigned u = __float_as_uint(f);
    return (u16)((u + 0x7FFF + ((u >> 16) & 1)) >> 16);
}

// ---------------- P0: fp32 -> bf16 copies of W and A ----------------
__global__ __launch_bounds__(256) void convert_bf16(
    const float* __restrict__ W, const float* __restrict__ A,
    u16* __restrict__ Wb, u16* __restrict__ Ab)
{
    const size_t NW = (size_t)DLAT * DK / 4;
    const size_t NA = (size_t)NROWS * DK / 4;
    size_t i = (size_t)blockIdx.x * 256 + threadIdx.x;
    const size_t stride = (size_t)gridDim.x * 256;
    for (; i < NW + NA; i += stride) {
        const float4 v = (i < NW) ? ((const float4*)W)[i] : ((const float4*)A)[i - NW];
        ushort4 o;
        o.x = f2bf(v.x); o.y = f2bf(v.y); o.z = f2bf(v.z); o.w = f2bf(v.w);
        if (i < NW) ((ushort4*)Wb)[i] = o; else ((ushort4*)Ab)[i - NW] = o;
    }
}

// ---------------- P1: 256x256 8-phase bf16 MFMA GEMM -> approx (u16 fixed point) ----------------
// LDS qrow layout: A: qrow = qm*128 + wm*64 + loc(0..63), global m = wm*128 + qm*64 + loc
//                  B: qrow = qn*128 + wn*32 + loc(0..31), global n = wn*64 + qn*32 + loc
// XOR swizzle on 16B slots: LDS[qrow][s] holds global slot s ^ (qrow&7)
// (stage pre-swizzles the per-lane GLOBAL address; ds_read applies the same XOR).

#define GLDS(src, dst) __builtin_amdgcn_global_load_lds( \
    (const __attribute__((address_space(1))) void*)(src), \
    (__attribute__((address_space(3))) void*)(dst), 16, 0, 0)

__device__ __forceinline__ void ld_afrag(bf16x8 af[4][2], const u16* sbuf,
                                         int qm, int wm, int lr, int lk, int l7) {
#pragma unroll
    for (int mf = 0; mf < 4; ++mf)
#pragma unroll
        for (int kk = 0; kk < 2; ++kk)
            af[mf][kk] = *(const bf16x8*)&sbuf[(qm * 128 + wm * 64 + mf * 16 + lr) * 64
                                               + (((kk * 4 + lk) ^ l7) * 8)];
}
__device__ __forceinline__ void ld_bfrag(bf16x8 bfr[2][2], const u16* sbuf,
                                         int qn, int wn, int lr, int lk, int l7) {
#pragma unroll
    for (int nf = 0; nf < 2; ++nf)
#pragma unroll
        for (int kk = 0; kk < 2; ++kk)
            bfr[nf][kk] = *(const bf16x8*)&sbuf[(qn * 128 + wn * 32 + nf * 16 + lr) * 64
                                                + (((kk * 4 + lk) ^ l7) * 8)];
}
__device__ __forceinline__ void mma_quad(f32x4 acc[8][4], const bf16x8 af[4][2],
                                         const bf16x8 bfr[2][2], int qm, int qn) {
#pragma unroll
    for (int mf = 0; mf < 4; ++mf)
#pragma unroll
        for (int nf = 0; nf < 2; ++nf)
#pragma unroll
            for (int kk = 0; kk < 2; ++kk)
                acc[qm * 4 + mf][qn * 2 + nf] = __builtin_amdgcn_mfma_f32_16x16x32_bf16(
                    af[mf][kk], bfr[nf][kk], acc[qm * 4 + mf][qn * 2 + nf], 0, 0, 0);
}

__global__ __launch_bounds__(512, 2) void gemm8(
    const u16* __restrict__ Ab, const u16* __restrict__ Wb,
    const float* __restrict__ bias, u16* __restrict__ approx)
{
    __shared__ __align__(16) u16 sm[4][256 * 64];   // A0,A1,B0,B1 = 128 KB
    u16* sAb[2] = { sm[0], sm[1] };
    u16* sBb[2] = { sm[2], sm[3] };

    const int tid = threadIdx.x;
    const int w = tid >> 6, l = tid & 63;
    const int wm = w >> 2, wn = w & 3;
    const int lr = l & 15, lk = l >> 4, l7 = l & 7;

    const int bid = blockIdx.x;
    const int swz = (bid & 7) * 256 + (bid >> 3);   // 2048 % 8 == 0: bijective
    const int rb = swz >> 7, cb = swz & 127;

    // per-lane pre-swizzled stage source pointers; wave-uniform LDS dests
    const int sub = l >> 3;
    const int ss  = (l & 7) ^ sub;                  // source slot = lds slot ^ (qrow&7)
    const u16* gA[4]; const u16* gB[4];
    u16* dA[2][4]; u16* dB[2][4];
#pragma unroll
    for (int c = 0; c < 4; ++c) {
        const int q  = c * 64 + w * 8 + sub;
        const int mA = ((q >> 6) & 1) * 128 + (q >> 7) * 64 + (q & 63);
        const int nB = ((q >> 5) & 3) * 64  + (q >> 7) * 32 + (q & 31);
        gA[c] = Ab + (size_t)(rb * 256 + mA) * DK + ss * 8;
        gB[c] = Wb + (size_t)(cb * 256 + nB) * DK + ss * 8;
#pragma unroll
        for (int bb = 0; bb < 2; ++bb) {
            dA[bb][c] = sAb[bb] + (c * 64 + w * 8) * 64;
            dB[bb][c] = sBb[bb] + (c * 64 + w * 8) * 64;
        }
    }

    f32x4 acc[8][4];
#pragma unroll
    for (int i = 0; i < 8; ++i)
#pragma unroll
        for (int j = 0; j < 4; ++j) acc[i][j] = (f32x4){0.f, 0.f, 0.f, 0.f};

    // prologue: stage tile 0 into buf0, order Aq0, Bq0, Bq1, Aq1
    GLDS(gA[0], dA[0][0]); GLDS(gA[1], dA[0][1]);
    GLDS(gB[0], dB[0][0]); GLDS(gB[1], dB[0][1]);
    GLDS(gB[2], dB[0][2]); GLDS(gB[3], dB[0][3]);
    GLDS(gA[2], dA[0][2]); GLDS(gA[3], dA[0][3]);

    bf16x8 af[4][2], bf0[2][2], bf1[2][2];

    for (int t = 0; t < 15; ++t) {
        const int b = t & 1;
        const u16* cA = sAb[b]; const u16* cB = sBb[b];
        const int ko = (t + 1) * 64;
        // ---- ph1: quadrant (0,0); stage Aq0(t+1)
        asm volatile("s_waitcnt vmcnt(4)" ::: "memory");
        __builtin_amdgcn_s_barrier();
        __builtin_amdgcn_sched_barrier(0);
        ld_afrag(af, cA, 0, wm, lr, lk, l7);
        ld_bfrag(bf0, cB, 0, wn, lr, lk, l7);
        GLDS(gA[0] + ko, dA[b ^ 1][0]); GLDS(gA[1] + ko, dA[b ^ 1][1]);
        __builtin_amdgcn_s_setprio(1);
        mma_quad(acc, af, bf0, 0, 0);
        __builtin_amdgcn_s_setprio(0);
        // ---- ph2: quadrant (0,1); stage Bq0(t+1)
        asm volatile("s_waitcnt vmcnt(4)" ::: "memory");
        __builtin_amdgcn_s_barrier();
        __builtin_amdgcn_sched_barrier(0);
        ld_bfrag(bf1, cB, 1, wn, lr, lk, l7);
        GLDS(gB[0] + ko, dB[b ^ 1][0]); GLDS(gB[1] + ko, dB[b ^ 1][1]);
        __builtin_amdgcn_s_setprio(1);
        mma_quad(acc, af, bf1, 0, 1);
        __builtin_amdgcn_s_setprio(0);
        // ---- ph3: quadrant (1,1); stage Bq1(t+1)
        asm volatile("s_waitcnt vmcnt(4)" ::: "memory");
        __builtin_amdgcn_s_barrier();
        __builtin_amdgcn_sched_barrier(0);
        ld_afrag(af, cA, 1, wm, lr, lk, l7);
        GLDS(gB[2] + ko, dB[b ^ 1][2]); GLDS(gB[3] + ko, dB[b ^ 1][3]);
        __builtin_amdgcn_s_setprio(1);
        mma_quad(acc, af, bf1, 1, 1);
        __builtin_amdgcn_s_setprio(0);
        // ---- ph4: quadrant (1,0) from registers; stage Aq1(t+1); no barrier needed
        GLDS(gA[2] + ko, dA[b ^ 1][2]); GLDS(gA[3] + ko, dA[b ^ 1][3]);
        __builtin_amdgcn_s_setprio(1);
        mma_quad(acc, af, bf0, 1, 0);
        __builtin_amdgcn_s_setprio(0);
    }
    { // tile 15 (buf 1), no staging; drain with counted waits
        const u16* cA = sAb[1]; const u16* cB = sBb[1];
        asm volatile("s_waitcnt vmcnt(4)" ::: "memory");
        __builtin_amdgcn_s_barrier();
        __builtin_amdgcn_sched_barrier(0);
        ld_afrag(af, cA, 0, wm, lr, lk, l7);
        ld_bfrag(bf0, cB, 0, wn, lr, lk, l7);
        __builtin_amdgcn_s_setprio(1);
        mma_quad(acc, af, bf0, 0, 0);
        __builtin_amdgcn_s_setprio(0);
        asm volatile("s_waitcnt vmcnt(2)" ::: "memory");
        __builtin_amdgcn_s_barrier();
        __builtin_amdgcn_sched_barrier(0);
        ld_bfrag(bf1, cB, 1, wn, lr, lk, l7);
        __builtin_amdgcn_s_setprio(1);
        mma_quad(acc, af, bf1, 0, 1);
        __builtin_amdgcn_s_setprio(0);
        asm volatile("s_waitcnt vmcnt(0)" ::: "memory");
        __builtin_amdgcn_s_barrier();
        __builtin_amdgcn_sched_barrier(0);
        ld_afrag(af, cA, 1, wm, lr, lk, l7);
        __builtin_amdgcn_s_setprio(1);
        mma_quad(acc, af, bf1, 1, 1);
        mma_quad(acc, af, bf0, 1, 0);
        __builtin_amdgcn_s_setprio(0);
    }

    // epilogue
    const int r0 = rb * 256 + wm * 128;
    const int c0 = cb * 256 + wn * 64;
#pragma unroll
    for (int jn = 0; jn < 4; ++jn) {
        const int col = c0 + (jn >> 1) * 32 + (jn & 1) * 16 + lr;
        const float bv = bias[col];
#pragma unroll
        for (int i = 0; i < 8; ++i) {
            const int mrow = r0 + (i >> 2) * 64 + (i & 3) * 16 + lk * 4;
#pragma unroll
            for (int r = 0; r < 4; ++r) {
                const float pre = acc[i][jn][r] + bv;
                int q = __float2int_rn(pre * 4096.f) + 32768;
                q = min(max(q, 0), 65535);
                approx[(size_t)(mrow + r) * DLAT + col] = (u16)q;
            }
        }
    }
}

// ---------------- P2: per-(row,level) histogram select + exact rescore + finalize ----------------
__global__ __launch_bounds__(256) void select_rescore_final(
    const u16* __restrict__ apx, const float* __restrict__ h2,
    const float* __restrict__ W, const float* __restrict__ bias,
    float* __restrict__ pv, int* __restrict__ pc)
{
    __shared__ int hist[4096];
    __shared__ __align__(16) float sAr[DK];
    __shared__ int wsum[4];
    __shared__ int s_B, s_ns, s_nb;
    __shared__ u16 bcol[BCAP];
    __shared__ float bpre[BCAP];

    const int tid = threadIdx.x, lane = tid & 63, wv = tid >> 6;
    const int u = blockIdx.x;
    const int row = u / 3, lvl = u - 3 * row;
    const int LSTART[3] = {0, 2048, 8192};
    const int LN[3]     = {2048, 6144, 24576};
    const int LK_[3]    = {32, 64, 128};
    const int PB_[3]    = {0, 32, 96};
    const int start = LSTART[lvl], n = LN[lvl], k = LK_[lvl], pbase = PB_[lvl];

    for (int i = tid; i < DK / 4; i += 256)
        ((float4*)sAr)[i] = ((const float4*)(h2 + (size_t)row * DK))[i];
#pragma unroll
    for (int i = 0; i < 16; ++i) hist[tid * 16 + i] = 0;
    if (tid == 0) { s_ns = 0; s_nb = 0; }
    __syncthreads();

    const uint4* base = (const uint4*)(apx + (size_t)row * DLAT + start);
    const int n8 = n >> 3;
    for (int i = tid; i < n8; i += 256) {
        const uint4 v = base[i];
        atomicAdd(&hist[(v.x & 0xFFFF) >> 4], 1);
        atomicAdd(&hist[(v.x >> 16) >> 4], 1);
        atomicAdd(&hist[(v.y & 0xFFFF) >> 4], 1);
        atomicAdd(&hist[(v.y >> 16) >> 4], 1);
        atomicAdd(&hist[(v.z & 0xFFFF) >> 4], 1);
        atomicAdd(&hist[(v.z >> 16) >> 4], 1);
        atomicAdd(&hist[(v.w & 0xFFFF) >> 4], 1);
        atomicAdd(&hist[(v.w >> 16) >> 4], 1);
    }
    __syncthreads();

    // suffix scan from top: chunk t covers bins [b0-15, b0], b0 = 4095-16t
    const int b0 = 4095 - 16 * tid;
    int part = 0;
#pragma unroll
    for (int i = 0; i < 16; ++i) part += hist[b0 - i];
    int incl = part;
#pragma unroll
    for (int s = 1; s < 64; s <<= 1) {
        const int t = __shfl_up(incl, s);
        if (lane >= s) incl += t;
    }
    if (lane == 63) wsum[wv] = incl;
    __syncthreads();
    int woff = 0;
    for (int j = 0; j < wv; ++j) woff += wsum[j];
    const int above = woff + incl - part;
    if (above < k && above + part >= k) {
        int run = above, B = -1;
        for (int i = 0; i < 16; ++i) {
            run += hist[b0 - i];
            if (run >= k) { B = b0 - i; break; }
        }
        s_B = B;
    }
    __syncthreads();

    const int qsure = s_B * 16 + 16 + EQ2;
    const int qband = s_B * 16 - EQ2;
    const size_t obase = (size_t)row * NPAIR + pbase;

    for (int i = tid; i < n8; i += 256) {
        const uint4 v = base[i];
        const int col0 = start + i * 8;
        unsigned qs[8] = { v.x & 0xFFFF, v.x >> 16, v.y & 0xFFFF, v.y >> 16,
                           v.z & 0xFFFF, v.z >> 16, v.w & 0xFFFF, v.w >> 16 };
#pragma unroll
        for (int j = 0; j < 8; ++j) {
            const int q = (int)qs[j];
            if (q >= qsure) {
                const int p = atomicAdd(&s_ns, 1);
                if (p < k) {
                    const float a = (q - 32768) * QINV;
                    pv[obase + p] = fmaxf(a, 0.f) + (a > 1.f ? 1.f : 0.f);
                    pc[obase + p] = col0 + j;
                }
            } else if (q >= qband) {
                const int p = atomicAdd(&s_nb, 1);
                if (p < BCAP) bcol[p] = (u16)(col0 + j);
            }
        }
    }
    __syncthreads();
    const int m  = min(s_ns, k);
    const int bc = min(s_nb, BCAP);

    // exact fp32 rescore of band, one wave per candidate
    for (int c = wv; c < bc; c += 4) {
        const int col = bcol[c];
        const float* wrow = W + (size_t)col * DK;
        float p = 0.f;
#pragma unroll
        for (int j = 0; j < 4; ++j) {
            const float4 w4 = ((const float4*)wrow)[j * 64 + lane];
            const float4 a4 = ((const float4*)sAr)[j * 64 + lane];
            p = fmaf(w4.x, a4.x, p); p = fmaf(w4.y, a4.y, p);
            p = fmaf(w4.z, a4.z, p); p = fmaf(w4.w, a4.w, p);
        }
#pragma unroll
        for (int s = 32; s; s >>= 1) p += __shfl_xor(p, s);
        if (lane == 0) bpre[c] = p + bias[col];
    }
    __syncthreads();

    // stable top-(k-m) among band by exact (pre desc, col asc)
    const int need = k - m;
    for (int c = tid; c < bc; c += 256) {
        const float pc_ = bpre[c];
        const int colc = bcol[c];
        int rank = 0;
        for (int d = 0; d < bc; ++d) {
            const float pd = bpre[d];
            rank += (pd > pc_) || (pd == pc_ && bcol[d] < colc);
        }
        if (rank < need) {
            pv[obase + m + rank] = fmaxf(pc_, 0.f) + (pc_ > 1.f ? 1.f : 0.f);
            pc[obase + m + rank] = colc;
        }
    }
}

// ---------------- P3: zero row + scatter its pairs ----------------
__global__ __launch_bounds__(256) void zero_scatter(
    const float* __restrict__ pv, const int* __restrict__ pc, float* __restrict__ Z)
{
    const int row = blockIdx.x, tid = threadIdx.x;
    float4* zr = (float4*)(Z + (size_t)row * DLAT);
    const float4 z4 = make_float4(0.f, 0.f, 0.f, 0.f);
#pragma unroll
    for (int i = 0; i < 32; ++i) zr[tid + i * 256] = z4;
    __syncthreads();
    if (tid < NPAIR) {
        const float v = pv[(size_t)row * NPAIR + tid];
        const int col = pc[(size_t)row * NPAIR + tid];
        Z[(size_t)row * DLAT + col] = v;
    }
}

extern "C" void kernel_launch(void* const* d_in, const int* in_sizes, int n_in,
                              void* d_out, int out_size, void* d_ws, size_t ws_size,
                              hipStream_t stream)
{
    const float* h2   = (const float*)d_in[0];
    const float* Wenc = (const float*)d_in[1];
    const float* benc = (const float*)d_in[2];
    char* ob = (char*)d_out;

    u16* approx = (u16*)ob;
    u16* Wb = (u16*)(ob + WB_OFF);
    u16* Ab = (u16*)(ob + AB_OFF);
    float* pv = (float*)d_ws;
    int*   pc = (int*)((char*)d_ws + (size_t)NROWS * NPAIR * 4);

    convert_bf16<<<2048, 256, 0, stream>>>(Wenc, h2, Wb, Ab);
    gemm8<<<2048, 512, 0, stream>>>(Ab, Wb, benc, approx);
    select_rescore_final<<<NUNIT, 256, 0, stream>>>(approx, h2, Wenc, benc, pv, pc);
    zero_scatter<<<NROWS, 256, 0, stream>>>(pv, pc, (float*)d_out);
}